// Round 4
// baseline (653.318 us; speedup 1.0000x reference)
//
#include <hip/hip_runtime.h>
#include <hip/hip_bf16.h>

#define B_ 4
#define C_ 256
#define N_ 4096

typedef unsigned short u16;
typedef __attribute__((ext_vector_type(8))) short bf16x8;
typedef __attribute__((ext_vector_type(4))) float f32x4;

static __device__ __forceinline__ u16 f2bf(float f) {
    unsigned u = __float_as_uint(f);
    unsigned r = (u + 0x7FFFu + ((u >> 16) & 1u)) >> 16;
    return (u16)r;
}
static __device__ __forceinline__ float bf2f(u16 u) {
    return __uint_as_float(((unsigned)u) << 16);
}

static __device__ __forceinline__ f32x4 mfma16(bf16x8 a, bf16x8 b, f32x4 c) {
    return __builtin_amdgcn_mfma_f32_16x16x32_bf16(a, b, c, 0, 0, 0);
}

// ---------------- kernel 1: weights f32 -> bf16 ----------------
__global__ void wconv_kernel(const float* __restrict__ wq, const float* __restrict__ wk,
                             const float* __restrict__ wv,
                             u16* __restrict__ wqb, u16* __restrict__ wkb, u16* __restrict__ wvb) {
    int i = blockIdx.x * blockDim.x + threadIdx.x;   // grid covers C_*C_
    wqb[i] = f2bf(wq[i]);
    wkb[i] = f2bf(wk[i]);
    wvb[i] = f2bf(wv[i]);
}

// ---------------- kernel 2: pose [B,C,N] f32 -> poseT [B,N,C] bf16 ----------------
__global__ void transpose_kernel(const float* __restrict__ pose, u16* __restrict__ poseT) {
    __shared__ float tile[64][65];
    int bid = blockIdx.x;              // B * 4 * 64 = 1024
    int b = bid >> 8;
    int rem = bid & 255;
    int ct = rem >> 6;                 // c-tile 0..3
    int nt = rem & 63;                 // n-tile 0..63
    int c0 = ct * 64, n0 = nt * 64;
    int tid = threadIdx.x;
    int lo = tid & 63, hi = tid >> 6;  // hi 0..3
#pragma unroll
    for (int r = 0; r < 16; ++r) {
        int cc = r * 4 + hi;
        tile[cc][lo] = pose[(size_t)(b * C_ + c0 + cc) * N_ + n0 + lo];
    }
    __syncthreads();
#pragma unroll
    for (int r = 0; r < 16; ++r) {
        int nn = r * 4 + hi;
        poseT[(size_t)(b * N_ + n0 + nn) * C_ + c0 + lo] = f2bf(tile[lo][nn]);
    }
}

// ---------------- kernel 3: projections ----------------
// Qm,Km: [B][N][C] bf16 ; Vm: [B][C][N] bf16
__global__ __launch_bounds__(256) void proj_kernel(
    const u16* __restrict__ poseT,
    const u16* __restrict__ wqb, const float* __restrict__ bq,
    const u16* __restrict__ wkb, const float* __restrict__ bk,
    const u16* __restrict__ wvb, const float* __restrict__ bv,
    u16* __restrict__ Qm, u16* __restrict__ Km, u16* __restrict__ Vm)
{
    int bid = blockIdx.x;              // B * N/64 = 256
    int b = bid >> 6;
    int n0 = (bid & 63) * 64;
    int lane = threadIdx.x & 63;
    int wav = threadIdx.x >> 6;        // 0..3
    int l15 = lane & 15, lg = lane >> 4;

    // ---- Q and K: out[n][d], wave owns 16 n-rows ----
    int nrow = n0 + wav * 16;
    const u16* arow = poseT + (size_t)(b * N_ + nrow + l15) * C_;
    bf16x8 afr[8];
#pragma unroll
    for (int kc = 0; kc < 8; ++kc)
        afr[kc] = *(const bf16x8*)(arow + kc * 32 + lg * 8);

    for (int qk = 0; qk < 2; ++qk) {
        const u16* wb = qk ? wkb : wqb;
        const float* bias = qk ? bk : bq;
        u16* outm = qk ? Km : Qm;
#pragma unroll
        for (int ct = 0; ct < 16; ++ct) {
            f32x4 acc = {0.f, 0.f, 0.f, 0.f};
            const u16* brow = wb + (size_t)(ct * 16 + l15) * C_;
#pragma unroll
            for (int kc = 0; kc < 8; ++kc) {
                bf16x8 bfr = *(const bf16x8*)(brow + kc * 32 + lg * 8);
                acc = mfma16(afr[kc], bfr, acc);
            }
            float bias_v = bias[ct * 16 + l15];
#pragma unroll
            for (int reg = 0; reg < 4; ++reg) {
                int nr = nrow + lg * 4 + reg;
                outm[(size_t)(b * N_ + nr) * C_ + ct * 16 + l15] = f2bf(acc[reg] + bias_v);
            }
        }
    }

    // ---- V: out[d][n], wave owns 64 d-rows ----
    int d0w = wav * 64;
#pragma unroll
    for (int dt = 0; dt < 4; ++dt) {
        const u16* awrow = wvb + (size_t)(d0w + dt * 16 + l15) * C_;
        bf16x8 av[8];
#pragma unroll
        for (int kc = 0; kc < 8; ++kc)
            av[kc] = *(const bf16x8*)(awrow + kc * 32 + lg * 8);
#pragma unroll
        for (int nt = 0; nt < 4; ++nt) {
            f32x4 acc = {0.f, 0.f, 0.f, 0.f};
            const u16* brow = poseT + (size_t)(b * N_ + n0 + nt * 16 + l15) * C_;
#pragma unroll
            for (int kc = 0; kc < 8; ++kc) {
                bf16x8 bfr = *(const bf16x8*)(brow + kc * 32 + lg * 8);
                acc = mfma16(av[kc], bfr, acc);
            }
#pragma unroll
            for (int reg = 0; reg < 4; ++reg) {
                int dd = d0w + dt * 16 + lg * 4 + reg;
                Vm[(size_t)(b * C_ + dd) * N_ + n0 + nt * 16 + l15] = f2bf(acc[reg] + bv[dd]);
            }
        }
    }
}

// ---------------- kernel 4: flash attention partial ----------------
// 512 threads = 8 waves: wave w -> i-rows (w&3)*16.., in-block j-quarter (w>>2)
// global j-split S=2 (s = bid&1 selects which half of N)
// pO[((s*B+b)*N + i)*C + c] bf16, referenced to block-common max pM/pL[(s*B+b)*N+i]
__global__ __launch_bounds__(512, 4) void attn_partial_kernel(
    const u16* __restrict__ Qm, const u16* __restrict__ Km, const u16* __restrict__ Vm,
    u16* __restrict__ pO, float* __restrict__ pM, float* __restrict__ pL)
{
    __shared__ __align__(16) u16 Plds[8][16][72];   // 18432 B
    __shared__ float mbuf[2][64], lbuf[2][64];
    __shared__ float obuf[64][66];                  // 16896 B

    int bid = blockIdx.x;              // 512
    int g = bid & 7;                   // (b,s): blocks with same g share K/V slice (XCD-local)
    int pos = bid >> 3;                // 0..63 i-tile
    int b = g >> 1;
    int s = g & 1;
    int i0 = pos * 64;

    int lane = threadIdx.x & 63;
    int w = threadIdx.x >> 6;          // 0..7
    int isub = w & 3;
    int par = w >> 2;                  // in-block j-quarter 0..1
    int l15 = lane & 15, lg = lane >> 4;

    const u16* qrow = Qm + (size_t)(b * N_ + i0 + isub * 16 + l15) * C_;
    bf16x8 qf[8];
#pragma unroll
    for (int kc = 0; kc < 8; ++kc) qf[kc] = *(const bf16x8*)(qrow + kc * 32 + lg * 8);

    f32x4 Ot[16];
#pragma unroll
    for (int ct = 0; ct < 16; ++ct) Ot[ct] = (f32x4){0.f, 0.f, 0.f, 0.f};
    float m_r[4] = {-1e30f, -1e30f, -1e30f, -1e30f};
    float l_r[4] = {0.f, 0.f, 0.f, 0.f};

    const u16* Kb = Km + (size_t)b * N_ * C_;
    const u16* Vb = Vm + (size_t)b * C_ * N_;

    int jt0 = (s * 2 + par) * 16;
    for (int jt = jt0; jt < jt0 + 16; ++jt) {
        int j0 = jt * 64;
        f32x4 sc[4];
#pragma unroll
        for (int t = 0; t < 4; ++t) sc[t] = (f32x4){0.f, 0.f, 0.f, 0.f};
#pragma unroll
        for (int t = 0; t < 4; ++t) {
            const u16* krow = Kb + (size_t)(j0 + t * 16 + l15) * C_;
#pragma unroll
            for (int kc = 0; kc < 8; ++kc) {
                bf16x8 kf = *(const bf16x8*)(krow + kc * 32 + lg * 8);
                sc[t] = mfma16(qf[kc], kf, sc[t]);
            }
        }
        // online softmax (rows: r = lg*4+reg, cols: t*16+l15)
        float scale_r[4];
#pragma unroll
        for (int reg = 0; reg < 4; ++reg) {
            float rm = fmaxf(fmaxf(sc[0][reg], sc[1][reg]), fmaxf(sc[2][reg], sc[3][reg]));
            rm = fmaxf(rm, __shfl_xor(rm, 1));
            rm = fmaxf(rm, __shfl_xor(rm, 2));
            rm = fmaxf(rm, __shfl_xor(rm, 4));
            rm = fmaxf(rm, __shfl_xor(rm, 8));
            float mn = fmaxf(m_r[reg], rm);
            scale_r[reg] = __expf(m_r[reg] - mn);
            m_r[reg] = mn;
            float rs = 0.f;
#pragma unroll
            for (int t = 0; t < 4; ++t) {
                float p = __expf(sc[t][reg] - mn);
                sc[t][reg] = p;
                rs += p;
            }
            rs += __shfl_xor(rs, 1);
            rs += __shfl_xor(rs, 2);
            rs += __shfl_xor(rs, 4);
            rs += __shfl_xor(rs, 8);
            l_r[reg] = l_r[reg] * scale_r[reg] + rs;
        }
#pragma unroll
        for (int ct = 0; ct < 16; ++ct)
#pragma unroll
            for (int reg = 0; reg < 4; ++reg)
                Ot[ct][reg] *= scale_r[reg];
        // P -> LDS (bf16), then re-read as A-fragments
#pragma unroll
        for (int t = 0; t < 4; ++t)
#pragma unroll
            for (int reg = 0; reg < 4; ++reg)
                Plds[w][lg * 4 + reg][t * 16 + l15] = f2bf(sc[t][reg]);

        bf16x8 af[2];
#pragma unroll
        for (int ks = 0; ks < 2; ++ks)
            af[ks] = *(const bf16x8*)(&Plds[w][l15][ks * 32 + lg * 8]);
#pragma unroll
        for (int ct = 0; ct < 16; ++ct) {
            const u16* vrow = Vb + (size_t)(ct * 16 + l15) * N_ + j0;
#pragma unroll
            for (int ks = 0; ks < 2; ++ks) {
                bf16x8 vf = *(const bf16x8*)(vrow + ks * 32 + lg * 8);
                Ot[ct] = mfma16(af[ks], vf, Ot[ct]);
            }
        }
    }

    // ---- in-block merge of the 2 j-quarters (wave pairs w, w+4) ----
    if (l15 == 0) {
#pragma unroll
        for (int reg = 0; reg < 4; ++reg) {
            mbuf[par][isub * 16 + lg * 4 + reg] = m_r[reg];
            lbuf[par][isub * 16 + lg * 4 + reg] = l_r[reg];
        }
    }
    __syncthreads();

    size_t rowbase = (size_t)(s * B_ + b) * N_ + i0 + isub * 16;
    float e_own[4];
#pragma unroll
    for (int reg = 0; reg < 4; ++reg) {
        int ig = isub * 16 + lg * 4 + reg;
        float m0 = mbuf[0][ig], m1 = mbuf[1][ig];
        float M = fmaxf(m0, m1);
        float e0 = __expf(m0 - M), e1 = __expf(m1 - M);
        float L = lbuf[0][ig] * e0 + lbuf[1][ig] * e1;
        e_own[reg] = par ? e1 : e0;
        if (par == 0 && l15 == 0) {
            size_t idx = rowbase + lg * 4 + reg;
            pM[idx] = M;
            pL[idx] = L;
        }
    }

#pragma unroll
    for (int cc = 0; cc < 4; ++cc) {
        __syncthreads();
        if (par == 1) {
#pragma unroll
            for (int u = 0; u < 4; ++u)
#pragma unroll
                for (int reg = 0; reg < 4; ++reg)
                    obuf[isub * 16 + lg * 4 + reg][u * 16 + l15] = Ot[cc * 4 + u][reg] * e_own[reg];
        }
        __syncthreads();
        if (par == 0) {
#pragma unroll
            for (int u = 0; u < 4; ++u)
#pragma unroll
                for (int reg = 0; reg < 4; ++reg) {
                    float v = obuf[isub * 16 + lg * 4 + reg][u * 16 + l15]
                            + Ot[cc * 4 + u][reg] * e_own[reg];
                    pO[(rowbase + lg * 4 + reg) * C_ + cc * 64 + u * 16 + l15] = f2bf(v);
                }
        }
    }
}

// ---------------- kernel 5: combine partials + residual ----------------
__global__ __launch_bounds__(256) void combine_kernel(
    const u16* __restrict__ pO, const float* __restrict__ pM, const float* __restrict__ pL,
    const float* __restrict__ pose, const float* __restrict__ gamma_p,
    float* __restrict__ out, int S)
{
    __shared__ float a_s[4][64];
    __shared__ float tile[64][65];

    int bid = blockIdx.x;              // B*4*64 = 1024
    int b = bid >> 8;
    int ct = (bid >> 6) & 3;
    int it = bid & 63;
    int c0 = ct * 64, i0 = it * 64;
    int tid = threadIdx.x;

    if (tid < 64) {
        int i = i0 + tid;
        float M = -1e30f;
        for (int s = 0; s < S; ++s)
            M = fmaxf(M, pM[(size_t)(s * B_ + b) * N_ + i]);
        float L = 0.f;
        for (int s = 0; s < S; ++s) {
            size_t idx = (size_t)(s * B_ + b) * N_ + i;
            L += pL[idx] * __expf(pM[idx] - M);
        }
        float invL = 1.0f / L;
        for (int s = 0; s < S; ++s) {
            size_t idx = (size_t)(s * B_ + b) * N_ + i;
            a_s[s][tid] = __expf(pM[idx] - M) * invL;
        }
    }
    __syncthreads();

    int lane = tid & 63, hi = tid >> 6;
#pragma unroll
    for (int r = 0; r < 16; ++r) {
        int il = r * 4 + hi;
        float acc = 0.f;
        for (int s = 0; s < S; ++s) {
            u16 u = pO[((size_t)(s * B_ + b) * N_ + i0 + il) * C_ + c0 + lane];
            acc += a_s[s][il] * bf2f(u);
        }
        tile[il][lane] = acc;
    }
    __syncthreads();

    float g = gamma_p[0];
#pragma unroll
    for (int r = 0; r < 16; ++r) {
        int cc = r * 4 + hi;
        size_t addr = (size_t)(b * C_ + c0 + cc) * N_ + i0 + lane;
        out[addr] = pose[addr] + g * tile[lane][cc];
    }
}

extern "C" void kernel_launch(void* const* d_in, const int* in_sizes, int n_in,
                              void* d_out, int out_size, void* d_ws, size_t ws_size,
                              hipStream_t stream) {
    (void)in_sizes; (void)n_in; (void)out_size; (void)ws_size;
    const float* pose = (const float*)d_in[0];
    const float* wq = (const float*)d_in[1];
    const float* bq = (const float*)d_in[2];
    const float* wk = (const float*)d_in[3];
    const float* bk = (const float*)d_in[4];
    const float* wv = (const float*)d_in[5];
    const float* bv = (const float*)d_in[6];
    const float* gamma = (const float*)d_in[7];
    float* out = (float*)d_out;

    const int S = 2;  // global j-split
    char* ws = (char*)d_ws;
    u16* wqb   = (u16*)(ws + 0);
    u16* wkb   = (u16*)(ws + (128 << 10));
    u16* wvb   = (u16*)(ws + (256 << 10));
    float* pM  = (float*)(ws + (384 << 10));     // S*B*N*4 = 128 KB
    float* pL  = pM + (size_t)S * B_ * N_;       // 128 KB  (ends < 1 MB)
    u16* Qm    = (u16*)(ws + (1 << 20));     // 8 MB
    u16* Km    = (u16*)(ws + (9 << 20));     // 8 MB
    u16* Vm    = (u16*)(ws + (17 << 20));    // 8 MB
    u16* poseT = (u16*)(ws + (25 << 20));    // 8 MB (dead after proj)
    u16* pO    = (u16*)(ws + (25 << 20));    // S*8 MB = 16 MB, aliases poseT -> 41 MB total

    hipLaunchKernelGGL(wconv_kernel, dim3(256), dim3(256), 0, stream, wq, wk, wv, wqb, wkb, wvb);
    hipLaunchKernelGGL(transpose_kernel, dim3(1024), dim3(256), 0, stream, pose, poseT);
    hipLaunchKernelGGL(proj_kernel, dim3(256), dim3(256), 0, stream,
                       poseT, wqb, bq, wkb, bk, wvb, bv, Qm, Km, Vm);
    hipLaunchKernelGGL(attn_partial_kernel, dim3(512), dim3(512), 0, stream,
                       Qm, Km, Vm, pO, pM, pL);
    hipLaunchKernelGGL(combine_kernel, dim3(1024), dim3(256), 0, stream,
                       pO, pM, pL, pose, gamma, out, S);
}

// Round 5
// 650.424 us; speedup vs baseline: 1.0044x; 1.0044x over previous
//
#include <hip/hip_runtime.h>
#include <hip/hip_bf16.h>

#define B_ 4
#define C_ 256
#define N_ 4096

typedef unsigned short u16;
typedef __attribute__((ext_vector_type(8))) short bf16x8;
typedef __attribute__((ext_vector_type(4))) float f32x4;

static __device__ __forceinline__ u16 f2bf(float f) {
    unsigned u = __float_as_uint(f);
    unsigned r = (u + 0x7FFFu + ((u >> 16) & 1u)) >> 16;
    return (u16)r;
}
static __device__ __forceinline__ float bf2f(u16 u) {
    return __uint_as_float(((unsigned)u) << 16);
}

static __device__ __forceinline__ f32x4 mfma16(bf16x8 a, bf16x8 b, f32x4 c) {
    return __builtin_amdgcn_mfma_f32_16x16x32_bf16(a, b, c, 0, 0, 0);
}

// ---------------- kernel 1: weights f32 -> bf16 ----------------
__global__ void wconv_kernel(const float* __restrict__ wq, const float* __restrict__ wk,
                             const float* __restrict__ wv,
                             u16* __restrict__ wqb, u16* __restrict__ wkb, u16* __restrict__ wvb) {
    int i = blockIdx.x * blockDim.x + threadIdx.x;   // grid covers C_*C_
    wqb[i] = f2bf(wq[i]);
    wkb[i] = f2bf(wk[i]);
    wvb[i] = f2bf(wv[i]);
}

// ---------------- kernel 2: pose [B,C,N] f32 -> poseT [B,N,C] bf16 ----------------
__global__ void transpose_kernel(const float* __restrict__ pose, u16* __restrict__ poseT) {
    __shared__ float tile[64][65];
    int bid = blockIdx.x;              // B * 4 * 64 = 1024
    int b = bid >> 8;
    int rem = bid & 255;
    int ct = rem >> 6;                 // c-tile 0..3
    int nt = rem & 63;                 // n-tile 0..63
    int c0 = ct * 64, n0 = nt * 64;
    int tid = threadIdx.x;
    int lo = tid & 63, hi = tid >> 6;  // hi 0..3
#pragma unroll
    for (int r = 0; r < 16; ++r) {
        int cc = r * 4 + hi;
        tile[cc][lo] = pose[(size_t)(b * C_ + c0 + cc) * N_ + n0 + lo];
    }
    __syncthreads();
#pragma unroll
    for (int r = 0; r < 16; ++r) {
        int nn = r * 4 + hi;
        poseT[(size_t)(b * N_ + n0 + nn) * C_ + c0 + lo] = f2bf(tile[lo][nn]);
    }
}

// ---------------- kernel 3: projections ----------------
// Qm,Km: [B][N][C] bf16 ; Vm: [B][C][N] bf16
__global__ __launch_bounds__(256) void proj_kernel(
    const u16* __restrict__ poseT,
    const u16* __restrict__ wqb, const float* __restrict__ bq,
    const u16* __restrict__ wkb, const float* __restrict__ bk,
    const u16* __restrict__ wvb, const float* __restrict__ bv,
    u16* __restrict__ Qm, u16* __restrict__ Km, u16* __restrict__ Vm)
{
    int bid = blockIdx.x;              // B * N/64 = 256
    int b = bid >> 6;
    int n0 = (bid & 63) * 64;
    int lane = threadIdx.x & 63;
    int wav = threadIdx.x >> 6;        // 0..3
    int l15 = lane & 15, lg = lane >> 4;

    // ---- Q and K: out[n][d], wave owns 16 n-rows ----
    int nrow = n0 + wav * 16;
    const u16* arow = poseT + (size_t)(b * N_ + nrow + l15) * C_;
    bf16x8 afr[8];
#pragma unroll
    for (int kc = 0; kc < 8; ++kc)
        afr[kc] = *(const bf16x8*)(arow + kc * 32 + lg * 8);

    for (int qk = 0; qk < 2; ++qk) {
        const u16* wb = qk ? wkb : wqb;
        const float* bias = qk ? bk : bq;
        u16* outm = qk ? Km : Qm;
#pragma unroll
        for (int ct = 0; ct < 16; ++ct) {
            f32x4 acc = {0.f, 0.f, 0.f, 0.f};
            const u16* brow = wb + (size_t)(ct * 16 + l15) * C_;
#pragma unroll
            for (int kc = 0; kc < 8; ++kc) {
                bf16x8 bfr = *(const bf16x8*)(brow + kc * 32 + lg * 8);
                acc = mfma16(afr[kc], bfr, acc);
            }
            float bias_v = bias[ct * 16 + l15];
#pragma unroll
            for (int reg = 0; reg < 4; ++reg) {
                int nr = nrow + lg * 4 + reg;
                outm[(size_t)(b * N_ + nr) * C_ + ct * 16 + l15] = f2bf(acc[reg] + bias_v);
            }
        }
    }

    // ---- V: out[d][n], wave owns 64 d-rows ----
    int d0w = wav * 64;
#pragma unroll
    for (int dt = 0; dt < 4; ++dt) {
        const u16* awrow = wvb + (size_t)(d0w + dt * 16 + l15) * C_;
        bf16x8 av[8];
#pragma unroll
        for (int kc = 0; kc < 8; ++kc)
            av[kc] = *(const bf16x8*)(awrow + kc * 32 + lg * 8);
#pragma unroll
        for (int nt = 0; nt < 4; ++nt) {
            f32x4 acc = {0.f, 0.f, 0.f, 0.f};
            const u16* brow = poseT + (size_t)(b * N_ + n0 + nt * 16 + l15) * C_;
#pragma unroll
            for (int kc = 0; kc < 8; ++kc) {
                bf16x8 bfr = *(const bf16x8*)(brow + kc * 32 + lg * 8);
                acc = mfma16(av[kc], bfr, acc);
            }
#pragma unroll
            for (int reg = 0; reg < 4; ++reg) {
                int dd = d0w + dt * 16 + lg * 4 + reg;
                Vm[(size_t)(b * C_ + dd) * N_ + n0 + nt * 16 + l15] = f2bf(acc[reg] + bv[dd]);
            }
        }
    }
}

// ---------------- kernel 4: flash attention partial ----------------
// 256 threads = 4 waves: wave w -> i-rows (w&1)*16.. of a 32-row i-tile,
// in-block j-half (w>>1); global j-split S=2 (s from block id).
// pO[((s*B+b)*N + i)*C + c] bf16, referenced to block-common max pM/pL[(s*B+b)*N+i]
__global__ __launch_bounds__(256, 4) void attn_partial_kernel(
    const u16* __restrict__ Qm, const u16* __restrict__ Km, const u16* __restrict__ Vm,
    u16* __restrict__ pO, float* __restrict__ pM, float* __restrict__ pL)
{
    __shared__ __align__(16) u16 Plds[4][16][72];   // 9216 B
    __shared__ float mbuf[2][32], lbuf[2][32];
    __shared__ float obuf[32][66];                  // 8448 B

    int bid = blockIdx.x;              // 1024
    int g = bid & 7;                   // (b,s): blocks with same g share K/V slice (XCD-local)
    int pos = bid >> 3;                // 0..127 i-tile (32 rows)
    int b = g >> 1;
    int s = g & 1;
    int i0 = pos * 32;

    int lane = threadIdx.x & 63;
    int w = threadIdx.x >> 6;          // 0..3
    int isub = w & 1;                  // i-subtile (16 rows)
    int par = w >> 1;                  // in-block j-half 0..1
    int l15 = lane & 15, lg = lane >> 4;

    const u16* qrow = Qm + (size_t)(b * N_ + i0 + isub * 16 + l15) * C_;
    bf16x8 qf[8];
#pragma unroll
    for (int kc = 0; kc < 8; ++kc) qf[kc] = *(const bf16x8*)(qrow + kc * 32 + lg * 8);

    f32x4 Ot[16];
#pragma unroll
    for (int ct = 0; ct < 16; ++ct) Ot[ct] = (f32x4){0.f, 0.f, 0.f, 0.f};
    float m_r[4] = {-1e30f, -1e30f, -1e30f, -1e30f};
    float l_r[4] = {0.f, 0.f, 0.f, 0.f};

    const u16* Kb = Km + (size_t)b * N_ * C_;
    const u16* Vb = Vm + (size_t)b * C_ * N_;

    int jt0 = (s * 2 + par) * 16;
    for (int jt = jt0; jt < jt0 + 16; ++jt) {
        int j0 = jt * 64;
        f32x4 sc[4];
#pragma unroll
        for (int t = 0; t < 4; ++t) sc[t] = (f32x4){0.f, 0.f, 0.f, 0.f};
#pragma unroll
        for (int t = 0; t < 4; ++t) {
            const u16* krow = Kb + (size_t)(j0 + t * 16 + l15) * C_;
#pragma unroll
            for (int kc = 0; kc < 8; ++kc) {
                bf16x8 kf = *(const bf16x8*)(krow + kc * 32 + lg * 8);
                sc[t] = mfma16(qf[kc], kf, sc[t]);
            }
        }
        // online softmax (rows: r = lg*4+reg, cols: t*16+l15)
        float scale_r[4];
#pragma unroll
        for (int reg = 0; reg < 4; ++reg) {
            float rm = fmaxf(fmaxf(sc[0][reg], sc[1][reg]), fmaxf(sc[2][reg], sc[3][reg]));
            rm = fmaxf(rm, __shfl_xor(rm, 1));
            rm = fmaxf(rm, __shfl_xor(rm, 2));
            rm = fmaxf(rm, __shfl_xor(rm, 4));
            rm = fmaxf(rm, __shfl_xor(rm, 8));
            float mn = fmaxf(m_r[reg], rm);
            scale_r[reg] = __expf(m_r[reg] - mn);
            m_r[reg] = mn;
            float rs = 0.f;
#pragma unroll
            for (int t = 0; t < 4; ++t) {
                float p = __expf(sc[t][reg] - mn);
                sc[t][reg] = p;
                rs += p;
            }
            rs += __shfl_xor(rs, 1);
            rs += __shfl_xor(rs, 2);
            rs += __shfl_xor(rs, 4);
            rs += __shfl_xor(rs, 8);
            l_r[reg] = l_r[reg] * scale_r[reg] + rs;
        }
#pragma unroll
        for (int ct = 0; ct < 16; ++ct)
#pragma unroll
            for (int reg = 0; reg < 4; ++reg)
                Ot[ct][reg] *= scale_r[reg];
        // P -> LDS (bf16), then re-read as A-fragments
#pragma unroll
        for (int t = 0; t < 4; ++t)
#pragma unroll
            for (int reg = 0; reg < 4; ++reg)
                Plds[w][lg * 4 + reg][t * 16 + l15] = f2bf(sc[t][reg]);

        bf16x8 af[2];
#pragma unroll
        for (int ks = 0; ks < 2; ++ks)
            af[ks] = *(const bf16x8*)(&Plds[w][l15][ks * 32 + lg * 8]);
#pragma unroll
        for (int ct = 0; ct < 16; ++ct) {
            const u16* vrow = Vb + (size_t)(ct * 16 + l15) * N_ + j0;
#pragma unroll
            for (int ks = 0; ks < 2; ++ks) {
                bf16x8 vf = *(const bf16x8*)(vrow + ks * 32 + lg * 8);
                Ot[ct] = mfma16(af[ks], vf, Ot[ct]);
            }
        }
    }

    // ---- in-block merge of the 2 j-halves (wave pairs w, w+2) ----
    if (l15 == 0) {
#pragma unroll
        for (int reg = 0; reg < 4; ++reg) {
            mbuf[par][isub * 16 + lg * 4 + reg] = m_r[reg];
            lbuf[par][isub * 16 + lg * 4 + reg] = l_r[reg];
        }
    }
    __syncthreads();

    size_t rowbase = (size_t)(s * B_ + b) * N_ + i0 + isub * 16;
    float e_own[4];
#pragma unroll
    for (int reg = 0; reg < 4; ++reg) {
        int ig = isub * 16 + lg * 4 + reg;
        float m0 = mbuf[0][ig], m1 = mbuf[1][ig];
        float M = fmaxf(m0, m1);
        float e0 = __expf(m0 - M), e1 = __expf(m1 - M);
        float L = lbuf[0][ig] * e0 + lbuf[1][ig] * e1;
        e_own[reg] = par ? e1 : e0;
        if (par == 0 && l15 == 0) {
            size_t idx = rowbase + lg * 4 + reg;
            pM[idx] = M;
            pL[idx] = L;
        }
    }

#pragma unroll
    for (int cc = 0; cc < 4; ++cc) {
        __syncthreads();
        if (par == 1) {
#pragma unroll
            for (int u = 0; u < 4; ++u)
#pragma unroll
                for (int reg = 0; reg < 4; ++reg)
                    obuf[isub * 16 + lg * 4 + reg][u * 16 + l15] = Ot[cc * 4 + u][reg] * e_own[reg];
        }
        __syncthreads();
        if (par == 0) {
#pragma unroll
            for (int u = 0; u < 4; ++u)
#pragma unroll
                for (int reg = 0; reg < 4; ++reg) {
                    float v = obuf[isub * 16 + lg * 4 + reg][u * 16 + l15]
                            + Ot[cc * 4 + u][reg] * e_own[reg];
                    pO[(rowbase + lg * 4 + reg) * C_ + cc * 64 + u * 16 + l15] = f2bf(v);
                }
        }
    }
}

// ---------------- kernel 5: combine partials + residual ----------------
__global__ __launch_bounds__(256) void combine_kernel(
    const u16* __restrict__ pO, const float* __restrict__ pM, const float* __restrict__ pL,
    const float* __restrict__ pose, const float* __restrict__ gamma_p,
    float* __restrict__ out, int S)
{
    __shared__ float a_s[4][64];
    __shared__ float tile[64][65];

    int bid = blockIdx.x;              // B*4*64 = 1024
    int b = bid >> 8;
    int ct = (bid >> 6) & 3;
    int it = bid & 63;
    int c0 = ct * 64, i0 = it * 64;
    int tid = threadIdx.x;

    if (tid < 64) {
        int i = i0 + tid;
        float M = -1e30f;
        for (int s = 0; s < S; ++s)
            M = fmaxf(M, pM[(size_t)(s * B_ + b) * N_ + i]);
        float L = 0.f;
        for (int s = 0; s < S; ++s) {
            size_t idx = (size_t)(s * B_ + b) * N_ + i;
            L += pL[idx] * __expf(pM[idx] - M);
        }
        float invL = 1.0f / L;
        for (int s = 0; s < S; ++s) {
            size_t idx = (size_t)(s * B_ + b) * N_ + i;
            a_s[s][tid] = __expf(pM[idx] - M) * invL;
        }
    }
    __syncthreads();

    int lane = tid & 63, hi = tid >> 6;
#pragma unroll
    for (int r = 0; r < 16; ++r) {
        int il = r * 4 + hi;
        float acc = 0.f;
        for (int s = 0; s < S; ++s) {
            u16 u = pO[((size_t)(s * B_ + b) * N_ + i0 + il) * C_ + c0 + lane];
            acc += a_s[s][il] * bf2f(u);
        }
        tile[il][lane] = acc;
    }
    __syncthreads();

    float g = gamma_p[0];
#pragma unroll
    for (int r = 0; r < 16; ++r) {
        int cc = r * 4 + hi;
        size_t addr = (size_t)(b * C_ + c0 + cc) * N_ + i0 + lane;
        out[addr] = pose[addr] + g * tile[lane][cc];
    }
}

extern "C" void kernel_launch(void* const* d_in, const int* in_sizes, int n_in,
                              void* d_out, int out_size, void* d_ws, size_t ws_size,
                              hipStream_t stream) {
    (void)in_sizes; (void)n_in; (void)out_size; (void)ws_size;
    const float* pose = (const float*)d_in[0];
    const float* wq = (const float*)d_in[1];
    const float* bq = (const float*)d_in[2];
    const float* wk = (const float*)d_in[3];
    const float* bk = (const float*)d_in[4];
    const float* wv = (const float*)d_in[5];
    const float* bv = (const float*)d_in[6];
    const float* gamma = (const float*)d_in[7];
    float* out = (float*)d_out;

    const int S = 2;  // global j-split
    char* ws = (char*)d_ws;
    u16* wqb   = (u16*)(ws + 0);
    u16* wkb   = (u16*)(ws + (128 << 10));
    u16* wvb   = (u16*)(ws + (256 << 10));
    float* pM  = (float*)(ws + (384 << 10));     // S*B*N*4 = 128 KB
    float* pL  = pM + (size_t)S * B_ * N_;       // 128 KB  (ends < 1 MB)
    u16* Qm    = (u16*)(ws + (1 << 20));     // 8 MB
    u16* Km    = (u16*)(ws + (9 << 20));     // 8 MB
    u16* Vm    = (u16*)(ws + (17 << 20));    // 8 MB
    u16* poseT = (u16*)(ws + (25 << 20));    // 8 MB (dead after proj)
    u16* pO    = (u16*)(ws + (25 << 20));    // S*8 MB = 16 MB, aliases poseT -> 41 MB total

    hipLaunchKernelGGL(wconv_kernel, dim3(256), dim3(256), 0, stream, wq, wk, wv, wqb, wkb, wvb);
    hipLaunchKernelGGL(transpose_kernel, dim3(1024), dim3(256), 0, stream, pose, poseT);
    hipLaunchKernelGGL(proj_kernel, dim3(256), dim3(256), 0, stream,
                       poseT, wqb, bq, wkb, bk, wvb, bv, Qm, Km, Vm);
    hipLaunchKernelGGL(attn_partial_kernel, dim3(1024), dim3(256), 0, stream,
                       Qm, Km, Vm, pO, pM, pL);
    hipLaunchKernelGGL(combine_kernel, dim3(1024), dim3(256), 0, stream,
                       pO, pM, pL, pose, gamma, out, S);
}

// Round 6
// 568.718 us; speedup vs baseline: 1.1488x; 1.1437x over previous
//
#include <hip/hip_runtime.h>
#include <hip/hip_bf16.h>

#define B_ 4
#define C_ 256
#define N_ 4096

typedef unsigned short u16;
typedef __attribute__((ext_vector_type(8))) short bf16x8;
typedef __attribute__((ext_vector_type(4))) float f32x4;

static __device__ __forceinline__ u16 f2bf(float f) {
    unsigned u = __float_as_uint(f);
    unsigned r = (u + 0x7FFFu + ((u >> 16) & 1u)) >> 16;
    return (u16)r;
}
static __device__ __forceinline__ float bf2f(u16 u) {
    return __uint_as_float(((unsigned)u) << 16);
}

static __device__ __forceinline__ f32x4 mfma16(bf16x8 a, bf16x8 b, f32x4 c) {
    return __builtin_amdgcn_mfma_f32_16x16x32_bf16(a, b, c, 0, 0, 0);
}

// ---------------- kernel 1: weights f32 -> bf16 ----------------
__global__ void wconv_kernel(const float* __restrict__ wq, const float* __restrict__ wk,
                             const float* __restrict__ wv,
                             u16* __restrict__ wqb, u16* __restrict__ wkb, u16* __restrict__ wvb) {
    int i = blockIdx.x * blockDim.x + threadIdx.x;   // grid covers C_*C_
    wqb[i] = f2bf(wq[i]);
    wkb[i] = f2bf(wk[i]);
    wvb[i] = f2bf(wv[i]);
}

// ---------------- kernel 2: pose [B,C,N] f32 -> poseT [B,N,C] bf16 ----------------
__global__ void transpose_kernel(const float* __restrict__ pose, u16* __restrict__ poseT) {
    __shared__ float tile[64][65];
    int bid = blockIdx.x;              // B * 4 * 64 = 1024
    int b = bid >> 8;
    int rem = bid & 255;
    int ct = rem >> 6;                 // c-tile 0..3
    int nt = rem & 63;                 // n-tile 0..63
    int c0 = ct * 64, n0 = nt * 64;
    int tid = threadIdx.x;
    int lo = tid & 63, hi = tid >> 6;  // hi 0..3
#pragma unroll
    for (int r = 0; r < 16; ++r) {
        int cc = r * 4 + hi;
        tile[cc][lo] = pose[(size_t)(b * C_ + c0 + cc) * N_ + n0 + lo];
    }
    __syncthreads();
#pragma unroll
    for (int r = 0; r < 16; ++r) {
        int nn = r * 4 + hi;
        poseT[(size_t)(b * N_ + n0 + nn) * C_ + c0 + lo] = f2bf(tile[lo][nn]);
    }
}

// ---------------- kernel 3: projections ----------------
// Qm,Km: [B][N][C] bf16 ; Vm: [B][C][N] bf16
__global__ __launch_bounds__(256) void proj_kernel(
    const u16* __restrict__ poseT,
    const u16* __restrict__ wqb, const float* __restrict__ bq,
    const u16* __restrict__ wkb, const float* __restrict__ bk,
    const u16* __restrict__ wvb, const float* __restrict__ bv,
    u16* __restrict__ Qm, u16* __restrict__ Km, u16* __restrict__ Vm)
{
    int bid = blockIdx.x;              // B * N/64 = 256
    int b = bid >> 6;
    int n0 = (bid & 63) * 64;
    int lane = threadIdx.x & 63;
    int wav = threadIdx.x >> 6;        // 0..3
    int l15 = lane & 15, lg = lane >> 4;

    // ---- Q and K: out[n][d], wave owns 16 n-rows ----
    int nrow = n0 + wav * 16;
    const u16* arow = poseT + (size_t)(b * N_ + nrow + l15) * C_;
    bf16x8 afr[8];
#pragma unroll
    for (int kc = 0; kc < 8; ++kc)
        afr[kc] = *(const bf16x8*)(arow + kc * 32 + lg * 8);

    for (int qk = 0; qk < 2; ++qk) {
        const u16* wb = qk ? wkb : wqb;
        const float* bias = qk ? bk : bq;
        u16* outm = qk ? Km : Qm;
#pragma unroll
        for (int ct = 0; ct < 16; ++ct) {
            f32x4 acc = {0.f, 0.f, 0.f, 0.f};
            const u16* brow = wb + (size_t)(ct * 16 + l15) * C_;
#pragma unroll
            for (int kc = 0; kc < 8; ++kc) {
                bf16x8 bfr = *(const bf16x8*)(brow + kc * 32 + lg * 8);
                acc = mfma16(afr[kc], bfr, acc);
            }
            float bias_v = bias[ct * 16 + l15];
#pragma unroll
            for (int reg = 0; reg < 4; ++reg) {
                int nr = nrow + lg * 4 + reg;
                outm[(size_t)(b * N_ + nr) * C_ + ct * 16 + l15] = f2bf(acc[reg] + bias_v);
            }
        }
    }

    // ---- V: out[d][n], wave owns 64 d-rows ----
    int d0w = wav * 64;
#pragma unroll
    for (int dt = 0; dt < 4; ++dt) {
        const u16* awrow = wvb + (size_t)(d0w + dt * 16 + l15) * C_;
        bf16x8 av[8];
#pragma unroll
        for (int kc = 0; kc < 8; ++kc)
            av[kc] = *(const bf16x8*)(awrow + kc * 32 + lg * 8);
#pragma unroll
        for (int nt = 0; nt < 4; ++nt) {
            f32x4 acc = {0.f, 0.f, 0.f, 0.f};
            const u16* brow = poseT + (size_t)(b * N_ + n0 + nt * 16 + l15) * C_;
#pragma unroll
            for (int kc = 0; kc < 8; ++kc) {
                bf16x8 bfr = *(const bf16x8*)(brow + kc * 32 + lg * 8);
                acc = mfma16(av[kc], bfr, acc);
            }
#pragma unroll
            for (int reg = 0; reg < 4; ++reg) {
                int dd = d0w + dt * 16 + lg * 4 + reg;
                Vm[(size_t)(b * C_ + dd) * N_ + n0 + nt * 16 + l15] = f2bf(acc[reg] + bv[dd]);
            }
        }
    }
}

// ---------------- kernel 4: flash attention partial ----------------
// 256 threads = 4 waves: wave w -> i-rows (w&1)*16.. of a 32-row i-tile,
// in-block j-half (w>>1); global j-split S=2 (s from block id).
// pO[((s*B+b)*N + i)*C + c] bf16, referenced to block-common max pM/pL[(s*B+b)*N+i]
// NOTE: bare __launch_bounds__(256) — any ",min_waves" hint makes the allocator
// cap at 64 VGPRs on this toolchain (proven rounds 3/4/5) and spill ~120 live regs.
__global__ __launch_bounds__(256) void attn_partial_kernel(
    const u16* __restrict__ Qm, const u16* __restrict__ Km, const u16* __restrict__ Vm,
    u16* __restrict__ pO, float* __restrict__ pM, float* __restrict__ pL)
{
    __shared__ __align__(16) u16 Plds[4][16][72];   // 9216 B
    __shared__ float mbuf[2][32], lbuf[2][32];
    __shared__ float obuf[32][66];                  // 8448 B

    int bid = blockIdx.x;              // 1024
    int g = bid & 7;                   // (b,s): blocks with same g share K/V slice (XCD-local)
    int pos = bid >> 3;                // 0..127 i-tile (32 rows)
    int b = g >> 1;
    int s = g & 1;
    int i0 = pos * 32;

    int lane = threadIdx.x & 63;
    int w = threadIdx.x >> 6;          // 0..3
    int isub = w & 1;                  // i-subtile (16 rows)
    int par = w >> 1;                  // in-block j-half 0..1
    int l15 = lane & 15, lg = lane >> 4;

    const u16* qrow = Qm + (size_t)(b * N_ + i0 + isub * 16 + l15) * C_;
    bf16x8 qf[8];
#pragma unroll
    for (int kc = 0; kc < 8; ++kc) qf[kc] = *(const bf16x8*)(qrow + kc * 32 + lg * 8);

    f32x4 Ot[16];
#pragma unroll
    for (int ct = 0; ct < 16; ++ct) Ot[ct] = (f32x4){0.f, 0.f, 0.f, 0.f};
    float m_r[4] = {-1e30f, -1e30f, -1e30f, -1e30f};
    float l_r[4] = {0.f, 0.f, 0.f, 0.f};

    const u16* Kb = Km + (size_t)b * N_ * C_;
    const u16* Vb = Vm + (size_t)b * C_ * N_;

    int jt0 = (s * 2 + par) * 16;
    for (int jt = jt0; jt < jt0 + 16; ++jt) {
        int j0 = jt * 64;
        f32x4 sc[4];
#pragma unroll
        for (int t = 0; t < 4; ++t) sc[t] = (f32x4){0.f, 0.f, 0.f, 0.f};
#pragma unroll
        for (int t = 0; t < 4; ++t) {
            const u16* krow = Kb + (size_t)(j0 + t * 16 + l15) * C_;
#pragma unroll
            for (int kc = 0; kc < 8; ++kc) {
                bf16x8 kf = *(const bf16x8*)(krow + kc * 32 + lg * 8);
                sc[t] = mfma16(qf[kc], kf, sc[t]);
            }
        }
        // online softmax (rows: r = lg*4+reg, cols: t*16+l15)
        float scale_r[4];
#pragma unroll
        for (int reg = 0; reg < 4; ++reg) {
            float rm = fmaxf(fmaxf(sc[0][reg], sc[1][reg]), fmaxf(sc[2][reg], sc[3][reg]));
            rm = fmaxf(rm, __shfl_xor(rm, 1));
            rm = fmaxf(rm, __shfl_xor(rm, 2));
            rm = fmaxf(rm, __shfl_xor(rm, 4));
            rm = fmaxf(rm, __shfl_xor(rm, 8));
            float mn = fmaxf(m_r[reg], rm);
            scale_r[reg] = __expf(m_r[reg] - mn);
            m_r[reg] = mn;
            float rs = 0.f;
#pragma unroll
            for (int t = 0; t < 4; ++t) {
                float p = __expf(sc[t][reg] - mn);
                sc[t][reg] = p;
                rs += p;
            }
            rs += __shfl_xor(rs, 1);
            rs += __shfl_xor(rs, 2);
            rs += __shfl_xor(rs, 4);
            rs += __shfl_xor(rs, 8);
            l_r[reg] = l_r[reg] * scale_r[reg] + rs;
        }
#pragma unroll
        for (int ct = 0; ct < 16; ++ct)
#pragma unroll
            for (int reg = 0; reg < 4; ++reg)
                Ot[ct][reg] *= scale_r[reg];
        // P -> LDS (bf16), then re-read as A-fragments
#pragma unroll
        for (int t = 0; t < 4; ++t)
#pragma unroll
            for (int reg = 0; reg < 4; ++reg)
                Plds[w][lg * 4 + reg][t * 16 + l15] = f2bf(sc[t][reg]);

        bf16x8 af[2];
#pragma unroll
        for (int ks = 0; ks < 2; ++ks)
            af[ks] = *(const bf16x8*)(&Plds[w][l15][ks * 32 + lg * 8]);
#pragma unroll
        for (int ct = 0; ct < 16; ++ct) {
            const u16* vrow = Vb + (size_t)(ct * 16 + l15) * N_ + j0;
#pragma unroll
            for (int ks = 0; ks < 2; ++ks) {
                bf16x8 vf = *(const bf16x8*)(vrow + ks * 32 + lg * 8);
                Ot[ct] = mfma16(af[ks], vf, Ot[ct]);
            }
        }
    }

    // ---- in-block merge of the 2 j-halves (wave pairs w, w+2) ----
    if (l15 == 0) {
#pragma unroll
        for (int reg = 0; reg < 4; ++reg) {
            mbuf[par][isub * 16 + lg * 4 + reg] = m_r[reg];
            lbuf[par][isub * 16 + lg * 4 + reg] = l_r[reg];
        }
    }
    __syncthreads();

    size_t rowbase = (size_t)(s * B_ + b) * N_ + i0 + isub * 16;
    float e_own[4];
#pragma unroll
    for (int reg = 0; reg < 4; ++reg) {
        int ig = isub * 16 + lg * 4 + reg;
        float m0 = mbuf[0][ig], m1 = mbuf[1][ig];
        float M = fmaxf(m0, m1);
        float e0 = __expf(m0 - M), e1 = __expf(m1 - M);
        float L = lbuf[0][ig] * e0 + lbuf[1][ig] * e1;
        e_own[reg] = par ? e1 : e0;
        if (par == 0 && l15 == 0) {
            size_t idx = rowbase + lg * 4 + reg;
            pM[idx] = M;
            pL[idx] = L;
        }
    }

#pragma unroll
    for (int cc = 0; cc < 4; ++cc) {
        __syncthreads();
        if (par == 1) {
#pragma unroll
            for (int u = 0; u < 4; ++u)
#pragma unroll
                for (int reg = 0; reg < 4; ++reg)
                    obuf[isub * 16 + lg * 4 + reg][u * 16 + l15] = Ot[cc * 4 + u][reg] * e_own[reg];
        }
        __syncthreads();
        if (par == 0) {
#pragma unroll
            for (int u = 0; u < 4; ++u)
#pragma unroll
                for (int reg = 0; reg < 4; ++reg) {
                    float v = obuf[isub * 16 + lg * 4 + reg][u * 16 + l15]
                            + Ot[cc * 4 + u][reg] * e_own[reg];
                    pO[(rowbase + lg * 4 + reg) * C_ + cc * 64 + u * 16 + l15] = f2bf(v);
                }
        }
    }
}

// ---------------- kernel 5: combine partials + residual ----------------
__global__ __launch_bounds__(256) void combine_kernel(
    const u16* __restrict__ pO, const float* __restrict__ pM, const float* __restrict__ pL,
    const float* __restrict__ pose, const float* __restrict__ gamma_p,
    float* __restrict__ out, int S)
{
    __shared__ float a_s[4][64];
    __shared__ float tile[64][65];

    int bid = blockIdx.x;              // B*4*64 = 1024
    int b = bid >> 8;
    int ct = (bid >> 6) & 3;
    int it = bid & 63;
    int c0 = ct * 64, i0 = it * 64;
    int tid = threadIdx.x;

    if (tid < 64) {
        int i = i0 + tid;
        float M = -1e30f;
        for (int s = 0; s < S; ++s)
            M = fmaxf(M, pM[(size_t)(s * B_ + b) * N_ + i]);
        float L = 0.f;
        for (int s = 0; s < S; ++s) {
            size_t idx = (size_t)(s * B_ + b) * N_ + i;
            L += pL[idx] * __expf(pM[idx] - M);
        }
        float invL = 1.0f / L;
        for (int s = 0; s < S; ++s) {
            size_t idx = (size_t)(s * B_ + b) * N_ + i;
            a_s[s][tid] = __expf(pM[idx] - M) * invL;
        }
    }
    __syncthreads();

    int lane = tid & 63, hi = tid >> 6;
#pragma unroll
    for (int r = 0; r < 16; ++r) {
        int il = r * 4 + hi;
        float acc = 0.f;
        for (int s = 0; s < S; ++s) {
            u16 u = pO[((size_t)(s * B_ + b) * N_ + i0 + il) * C_ + c0 + lane];
            acc += a_s[s][il] * bf2f(u);
        }
        tile[il][lane] = acc;
    }
    __syncthreads();

    float g = gamma_p[0];
#pragma unroll
    for (int r = 0; r < 16; ++r) {
        int cc = r * 4 + hi;
        size_t addr = (size_t)(b * C_ + c0 + cc) * N_ + i0 + lane;
        out[addr] = pose[addr] + g * tile[lane][cc];
    }
}

extern "C" void kernel_launch(void* const* d_in, const int* in_sizes, int n_in,
                              void* d_out, int out_size, void* d_ws, size_t ws_size,
                              hipStream_t stream) {
    (void)in_sizes; (void)n_in; (void)out_size; (void)ws_size;
    const float* pose = (const float*)d_in[0];
    const float* wq = (const float*)d_in[1];
    const float* bq = (const float*)d_in[2];
    const float* wk = (const float*)d_in[3];
    const float* bk = (const float*)d_in[4];
    const float* wv = (const float*)d_in[5];
    const float* bv = (const float*)d_in[6];
    const float* gamma = (const float*)d_in[7];
    float* out = (float*)d_out;

    const int S = 2;  // global j-split
    char* ws = (char*)d_ws;
    u16* wqb   = (u16*)(ws + 0);
    u16* wkb   = (u16*)(ws + (128 << 10));
    u16* wvb   = (u16*)(ws + (256 << 10));
    float* pM  = (float*)(ws + (384 << 10));     // S*B*N*4 = 128 KB
    float* pL  = pM + (size_t)S * B_ * N_;       // 128 KB  (ends < 1 MB)
    u16* Qm    = (u16*)(ws + (1 << 20));     // 8 MB
    u16* Km    = (u16*)(ws + (9 << 20));     // 8 MB
    u16* Vm    = (u16*)(ws + (17 << 20));    // 8 MB
    u16* poseT = (u16*)(ws + (25 << 20));    // 8 MB (dead after proj)
    u16* pO    = (u16*)(ws + (25 << 20));    // S*8 MB = 16 MB, aliases poseT -> 41 MB total

    hipLaunchKernelGGL(wconv_kernel, dim3(256), dim3(256), 0, stream, wq, wk, wv, wqb, wkb, wvb);
    hipLaunchKernelGGL(transpose_kernel, dim3(1024), dim3(256), 0, stream, pose, poseT);
    hipLaunchKernelGGL(proj_kernel, dim3(256), dim3(256), 0, stream,
                       poseT, wqb, bq, wkb, bk, wvb, bv, Qm, Km, Vm);
    hipLaunchKernelGGL(attn_partial_kernel, dim3(1024), dim3(256), 0, stream,
                       Qm, Km, Vm, pO, pM, pL);
    hipLaunchKernelGGL(combine_kernel, dim3(1024), dim3(256), 0, stream,
                       pO, pM, pL, pose, gamma, out, S);
}

// Round 7
// 277.947 us; speedup vs baseline: 2.3505x; 2.0461x over previous
//
#include <hip/hip_runtime.h>
#include <hip/hip_bf16.h>

#define B_ 4
#define C_ 256
#define N_ 4096

typedef unsigned short u16;
typedef __attribute__((ext_vector_type(8))) short bf16x8;
typedef __attribute__((ext_vector_type(4))) float f32x4;
typedef __attribute__((ext_vector_type(4))) unsigned u32x4;

static __device__ __forceinline__ u16 f2bf(float f) {
    unsigned u = __float_as_uint(f);
    unsigned r = (u + 0x7FFFu + ((u >> 16) & 1u)) >> 16;
    return (u16)r;
}
static __device__ __forceinline__ float bf2f(u16 u) {
    return __uint_as_float(((unsigned)u) << 16);
}

static __device__ __forceinline__ f32x4 mfma16(bf16x8 a, bf16x8 b, f32x4 c) {
    return __builtin_amdgcn_mfma_f32_16x16x32_bf16(a, b, c, 0, 0, 0);
}

// Fragment-swizzled layouts (u16 offsets within one batch):
// Q/K [N][C]: fragment (row16-tile, col32-chunk) stored as 64 lanes x 8 u16 contiguous.
static __device__ __forceinline__ int swzQK(int row, int col) {
    return ((row >> 4) * 8 + (col >> 5)) * 512 + ((col >> 3) & 3) * 128 + (row & 15) * 8 + (col & 7);
}
// V [C][N]: per 32-j granule: [d16-tile][lane][e] contiguous.
static __device__ __forceinline__ int swzV(int d, int j) {
    return ((j >> 5) * 16 + (d >> 4)) * 512 + ((j >> 3) & 3) * 128 + (d & 15) * 8 + (j & 7);
}

typedef const __attribute__((address_space(1))) void* gas1_t;
typedef __attribute__((address_space(3))) void* las3_t;
static __device__ __forceinline__ void gll16(const u16* g, u16* l) {
    __builtin_amdgcn_global_load_lds((gas1_t)(const void*)g, (las3_t)(void*)l, 16, 0, 0);
}

// ---------------- kernel 1: weights f32 -> bf16 ----------------
__global__ void wconv_kernel(const float* __restrict__ wq, const float* __restrict__ wk,
                             const float* __restrict__ wv,
                             u16* __restrict__ wqb, u16* __restrict__ wkb, u16* __restrict__ wvb) {
    int i = blockIdx.x * blockDim.x + threadIdx.x;
    wqb[i] = f2bf(wq[i]);
    wkb[i] = f2bf(wk[i]);
    wvb[i] = f2bf(wv[i]);
}

// ---------------- kernel 2: pose [B,C,N] f32 -> poseT [B,N,C] bf16 ----------------
__global__ void transpose_kernel(const float* __restrict__ pose, u16* __restrict__ poseT) {
    __shared__ float tile[64][65];
    int bid = blockIdx.x;              // B * 4 * 64 = 1024
    int b = bid >> 8;
    int rem = bid & 255;
    int ct = rem >> 6;
    int nt = rem & 63;
    int c0 = ct * 64, n0 = nt * 64;
    int tid = threadIdx.x;
    int lo = tid & 63, hi = tid >> 6;
#pragma unroll
    for (int r = 0; r < 16; ++r) {
        int cc = r * 4 + hi;
        tile[cc][lo] = pose[(size_t)(b * C_ + c0 + cc) * N_ + n0 + lo];
    }
    __syncthreads();
#pragma unroll
    for (int r = 0; r < 16; ++r) {
        int nn = r * 4 + hi;
        poseT[(size_t)(b * N_ + n0 + nn) * C_ + c0 + lo] = f2bf(tile[lo][nn]);
    }
}

// ---------------- kernel 3: projections (outputs in fragment-swizzled layouts) ----------------
__global__ __launch_bounds__(256) void proj_kernel(
    const u16* __restrict__ poseT,
    const u16* __restrict__ wqb, const float* __restrict__ bq,
    const u16* __restrict__ wkb, const float* __restrict__ bk,
    const u16* __restrict__ wvb, const float* __restrict__ bv,
    u16* __restrict__ Qm, u16* __restrict__ Km, u16* __restrict__ Vm)
{
    int bid = blockIdx.x;              // B * N/64 = 256
    int b = bid >> 6;
    int n0 = (bid & 63) * 64;
    int lane = threadIdx.x & 63;
    int wav = threadIdx.x >> 6;
    int l15 = lane & 15, lg = lane >> 4;

    // ---- Q and K: wave owns 16 n-rows ----
    int nrow = n0 + wav * 16;
    const u16* arow = poseT + (size_t)(b * N_ + nrow + l15) * C_;
    bf16x8 afr[8];
#pragma unroll
    for (int kc = 0; kc < 8; ++kc)
        afr[kc] = *(const bf16x8*)(arow + kc * 32 + lg * 8);

    for (int qk = 0; qk < 2; ++qk) {
        const u16* wb = qk ? wkb : wqb;
        const float* bias = qk ? bk : bq;
        u16* outm = qk ? Km : Qm;
#pragma unroll
        for (int ct = 0; ct < 16; ++ct) {
            f32x4 acc = {0.f, 0.f, 0.f, 0.f};
            const u16* brow = wb + (size_t)(ct * 16 + l15) * C_;
#pragma unroll
            for (int kc = 0; kc < 8; ++kc) {
                bf16x8 bfr = *(const bf16x8*)(brow + kc * 32 + lg * 8);
                acc = mfma16(afr[kc], bfr, acc);
            }
            float bias_v = bias[ct * 16 + l15];
#pragma unroll
            for (int reg = 0; reg < 4; ++reg) {
                int nr = nrow + lg * 4 + reg;
                outm[(size_t)b * N_ * C_ + swzQK(nr, ct * 16 + l15)] = f2bf(acc[reg] + bias_v);
            }
        }
    }

    // ---- V: wave owns 64 d-rows ----
    int d0w = wav * 64;
#pragma unroll
    for (int dt = 0; dt < 4; ++dt) {
        const u16* awrow = wvb + (size_t)(d0w + dt * 16 + l15) * C_;
        bf16x8 av[8];
#pragma unroll
        for (int kc = 0; kc < 8; ++kc)
            av[kc] = *(const bf16x8*)(awrow + kc * 32 + lg * 8);
#pragma unroll
        for (int nt = 0; nt < 4; ++nt) {
            f32x4 acc = {0.f, 0.f, 0.f, 0.f};
            const u16* brow = poseT + (size_t)(b * N_ + n0 + nt * 16 + l15) * C_;
#pragma unroll
            for (int kc = 0; kc < 8; ++kc) {
                bf16x8 bfr = *(const bf16x8*)(brow + kc * 32 + lg * 8);
                acc = mfma16(av[kc], bfr, acc);
            }
#pragma unroll
            for (int reg = 0; reg < 4; ++reg) {
                int dd = d0w + dt * 16 + lg * 4 + reg;
                Vm[(size_t)b * C_ * N_ + swzV(dd, n0 + nt * 16 + l15)] = f2bf(acc[reg] + bv[dd]);
            }
        }
    }
}

// ---------------- kernel 4: flash attention partial (LDS-staged K/V) ----------------
// 256 threads = 4 waves, each wave owns 16 i-rows of a 64-row i-tile; all waves
// share the K/V j-tile (KBLK=32) staged in LDS via global_load_lds.
// Global j-split S: block (b,s) sweeps j in [s*N/S, (s+1)*N/S).
// NOTE: bare __launch_bounds__(256) — any ",min_waves" hint caps VGPR at 64 on
// this toolchain (rounds 3/4/5) and spills catastrophically.
__global__ __launch_bounds__(256) void attn_partial_kernel(
    const u16* __restrict__ Qs, const u16* __restrict__ Ks, const u16* __restrict__ Vs,
    u16* __restrict__ pO, float* __restrict__ pM, float* __restrict__ pL,
    int S, int njt)
{
    __shared__ __align__(16) char smem[33792];   // K 16KB | V 16KB ; epilogue: obuf f32[64][66]
    __shared__ __align__(16) u16 Plds[4][16][40];

    u16* Klds = (u16*)smem;
    u16* Vlds = (u16*)(smem + 16384);

    int G = B_ * S;
    int bid = blockIdx.x;               // 64 * G
    int g = bid % G;                    // blocks with same g share a K/V slice (XCD-local at G=8)
    int pos = bid / G;                  // 0..63 i-tile
    int b = g / S;
    int s = g % S;
    int i0 = pos * 64;

    int tid = threadIdx.x;
    int lane = tid & 63;
    int w = tid >> 6;                   // i-subtile 0..3
    int l15 = lane & 15, lg = lane >> 4;

    // Q fragments (swizzled layout: each load is 64 lanes x 16B contiguous)
    const u16* Qb = Qs + (size_t)b * N_ * C_ + (size_t)(pos * 4 + w) * 4096 + lane * 8;
    bf16x8 qf[8];
#pragma unroll
    for (int kc = 0; kc < 8; ++kc) qf[kc] = *(const bf16x8*)(Qb + kc * 512);

    f32x4 Ot[16];
#pragma unroll
    for (int ct = 0; ct < 16; ++ct) Ot[ct] = (f32x4){0.f, 0.f, 0.f, 0.f};
    float m_r[4] = {-1e30f, -1e30f, -1e30f, -1e30f};
    float l_r[4] = {0.f, 0.f, 0.f, 0.f};

    const u16* Kb = Ks + (size_t)b * N_ * C_;
    const u16* Vb = Vs + (size_t)b * C_ * N_;
    int halfN = N_ / S;

    for (int jt = 0; jt < njt; ++jt) {
        int j0 = s * halfN + jt * 32;
        const u16* Ksrc = Kb + (size_t)(j0 >> 4) * 4096;
        const u16* Vsrc = Vb + (size_t)(j0 >> 5) * 8192;
#pragma unroll
        for (int q = 0; q < 4; ++q) {
            int v = q * 256 + tid;
            gll16(Ksrc + v * 8, Klds + v * 8);
            gll16(Vsrc + v * 8, Vlds + v * 8);
        }
        __syncthreads();

        // QK^T: sc rows = i (lg*4+reg), cols = j (t*16 + l15)
        f32x4 sc0 = {0.f, 0.f, 0.f, 0.f}, sc1 = {0.f, 0.f, 0.f, 0.f};
#pragma unroll
        for (int kc = 0; kc < 8; ++kc) {
            bf16x8 k0 = *(const bf16x8*)(Klds + kc * 512 + lane * 8);
            bf16x8 k1 = *(const bf16x8*)(Klds + 4096 + kc * 512 + lane * 8);
            sc0 = mfma16(qf[kc], k0, sc0);
            sc1 = mfma16(qf[kc], k1, sc1);
        }

        // online softmax over 32 j
        float scale_r[4];
#pragma unroll
        for (int reg = 0; reg < 4; ++reg) {
            float rm = fmaxf(sc0[reg], sc1[reg]);
            rm = fmaxf(rm, __shfl_xor(rm, 1));
            rm = fmaxf(rm, __shfl_xor(rm, 2));
            rm = fmaxf(rm, __shfl_xor(rm, 4));
            rm = fmaxf(rm, __shfl_xor(rm, 8));
            float mn = fmaxf(m_r[reg], rm);
            scale_r[reg] = __expf(m_r[reg] - mn);
            m_r[reg] = mn;
            float p0 = __expf(sc0[reg] - mn);
            float p1 = __expf(sc1[reg] - mn);
            sc0[reg] = p0; sc1[reg] = p1;
            float rs = p0 + p1;
            rs += __shfl_xor(rs, 1);
            rs += __shfl_xor(rs, 2);
            rs += __shfl_xor(rs, 4);
            rs += __shfl_xor(rs, 8);
            l_r[reg] = l_r[reg] * scale_r[reg] + rs;
        }
#pragma unroll
        for (int ct = 0; ct < 16; ++ct)
#pragma unroll
            for (int reg = 0; reg < 4; ++reg) Ot[ct][reg] *= scale_r[reg];

        // P -> LDS (bf16) -> A-fragment
#pragma unroll
        for (int reg = 0; reg < 4; ++reg) {
            Plds[w][lg * 4 + reg][l15]      = f2bf(sc0[reg]);
            Plds[w][lg * 4 + reg][16 + l15] = f2bf(sc1[reg]);
        }
        bf16x8 af = *(const bf16x8*)(&Plds[w][l15][lg * 8]);

        // PV: one MFMA per 16-d chunk
#pragma unroll
        for (int ct = 0; ct < 16; ++ct) {
            bf16x8 vf = *(const bf16x8*)(Vlds + ct * 512 + lane * 8);
            Ot[ct] = mfma16(af, vf, Ot[ct]);
        }
        __syncthreads();
    }

    // ---- epilogue: per-block partial (own m,l), coalesced pO stores via obuf ----
    size_t rowb = (size_t)(s * B_ + b) * N_ + i0 + w * 16;
    if (l15 == 0) {
#pragma unroll
        for (int reg = 0; reg < 4; ++reg) {
            pM[rowb + lg * 4 + reg] = m_r[reg];
            pL[rowb + lg * 4 + reg] = l_r[reg];
        }
    }
    float* obuf = (float*)smem;   // [64][66], aliases K/V LDS (main loop done)
    size_t prow = (size_t)(s * B_ + b) * N_ + i0;
#pragma unroll
    for (int cc = 0; cc < 4; ++cc) {
#pragma unroll
        for (int u = 0; u < 4; ++u)
#pragma unroll
            for (int reg = 0; reg < 4; ++reg)
                obuf[(w * 16 + lg * 4 + reg) * 66 + u * 16 + l15] = Ot[cc * 4 + u][reg];
        __syncthreads();
#pragma unroll
        for (int h = 0; h < 2; ++h) {
            int v = h * 256 + tid;
            int row = v >> 3, cg = v & 7;
            const float* src = obuf + row * 66 + cg * 8;
            u32x4 pk;
#pragma unroll
            for (int k = 0; k < 4; ++k)
                pk[k] = (unsigned)f2bf(src[2 * k]) | ((unsigned)f2bf(src[2 * k + 1]) << 16);
            *(u32x4*)(pO + (prow + row) * C_ + cc * 64 + cg * 8) = pk;
        }
        __syncthreads();
    }
}

// ---------------- kernel 5: combine partials + residual ----------------
__global__ __launch_bounds__(256) void combine_kernel(
    const u16* __restrict__ pO, const float* __restrict__ pM, const float* __restrict__ pL,
    const float* __restrict__ pose, const float* __restrict__ gamma_p,
    float* __restrict__ out, int S)
{
    __shared__ float a_s[4][64];
    __shared__ float tile[64][65];

    int bid = blockIdx.x;              // B*4*64 = 1024
    int b = bid >> 8;
    int ct = (bid >> 6) & 3;
    int it = bid & 63;
    int c0 = ct * 64, i0 = it * 64;
    int tid = threadIdx.x;

    if (tid < 64) {
        int i = i0 + tid;
        float M = -1e30f;
        for (int s = 0; s < S; ++s)
            M = fmaxf(M, pM[(size_t)(s * B_ + b) * N_ + i]);
        float L = 0.f;
        for (int s = 0; s < S; ++s) {
            size_t idx = (size_t)(s * B_ + b) * N_ + i;
            L += pL[idx] * __expf(pM[idx] - M);
        }
        float invL = 1.0f / L;
        for (int s = 0; s < S; ++s) {
            size_t idx = (size_t)(s * B_ + b) * N_ + i;
            a_s[s][tid] = __expf(pM[idx] - M) * invL;
        }
    }
    __syncthreads();

    int lane = tid & 63, hi = tid >> 6;
#pragma unroll
    for (int r = 0; r < 16; ++r) {
        int il = r * 4 + hi;
        float acc = 0.f;
        for (int s = 0; s < S; ++s) {
            u16 u = pO[((size_t)(s * B_ + b) * N_ + i0 + il) * C_ + c0 + lane];
            acc += a_s[s][il] * bf2f(u);
        }
        tile[il][lane] = acc;
    }
    __syncthreads();

    float g = gamma_p[0];
#pragma unroll
    for (int r = 0; r < 16; ++r) {
        int cc = r * 4 + hi;
        size_t addr = (size_t)(b * C_ + c0 + cc) * N_ + i0 + lane;
        out[addr] = pose[addr] + g * tile[lane][cc];
    }
}

extern "C" void kernel_launch(void* const* d_in, const int* in_sizes, int n_in,
                              void* d_out, int out_size, void* d_ws, size_t ws_size,
                              hipStream_t stream) {
    (void)in_sizes; (void)n_in; (void)out_size;
    const float* pose = (const float*)d_in[0];
    const float* wq = (const float*)d_in[1];
    const float* bq = (const float*)d_in[2];
    const float* wk = (const float*)d_in[3];
    const float* bk = (const float*)d_in[4];
    const float* wv = (const float*)d_in[5];
    const float* bv = (const float*)d_in[6];
    const float* gamma = (const float*)d_in[7];
    float* out = (float*)d_out;

    const int S = (ws_size >= ((size_t)57 << 20)) ? 4 : 2;   // global j-split
    char* ws = (char*)d_ws;
    u16* wqb   = (u16*)(ws + 0);
    u16* wkb   = (u16*)(ws + (128 << 10));
    u16* wvb   = (u16*)(ws + (256 << 10));
    float* pM  = (float*)(ws + (384 << 10));     // up to 256 KB (S=4)
    float* pL  = pM + (size_t)S * B_ * N_;       // ends < 1 MB
    u16* Qm    = (u16*)(ws + (1 << 20));     // 8 MB (swizzled)
    u16* Km    = (u16*)(ws + (9 << 20));     // 8 MB (swizzled)
    u16* Vm    = (u16*)(ws + (17 << 20));    // 8 MB (swizzled)
    u16* poseT = (u16*)(ws + (25 << 20));    // 8 MB (dead after proj)
    u16* pO    = (u16*)(ws + (25 << 20));    // S*8 MB, aliases poseT

    int njt = (N_ / S) / 32;

    hipLaunchKernelGGL(wconv_kernel, dim3(256), dim3(256), 0, stream, wq, wk, wv, wqb, wkb, wvb);
    hipLaunchKernelGGL(transpose_kernel, dim3(1024), dim3(256), 0, stream, pose, poseT);
    hipLaunchKernelGGL(proj_kernel, dim3(256), dim3(256), 0, stream,
                       poseT, wqb, bq, wkb, bk, wvb, bv, Qm, Km, Vm);
    hipLaunchKernelGGL(attn_partial_kernel, dim3(64 * B_ * S), dim3(256), 0, stream,
                       Qm, Km, Vm, pO, pM, pL, S, njt);
    hipLaunchKernelGGL(combine_kernel, dim3(1024), dim3(256), 0, stream,
                       pO, pM, pL, pose, gamma, out, S);
}

// Round 9
// 227.508 us; speedup vs baseline: 2.8716x; 1.2217x over previous
//
#include <hip/hip_runtime.h>
#include <hip/hip_bf16.h>

#define B_ 4
#define C_ 256
#define N_ 4096
#define LOG2E 1.4426950408889634f
#define THR_L2 11.5415603f   // 8 * log2(e), defer-max threshold in log2 domain

typedef unsigned short u16;
typedef __attribute__((ext_vector_type(8))) short bf16x8;
typedef __attribute__((ext_vector_type(4))) float f32x4;
typedef __attribute__((ext_vector_type(4))) unsigned u32x4;

static __device__ __forceinline__ u16 f2bf(float f) {
    unsigned u = __float_as_uint(f);
    unsigned r = (u + 0x7FFFu + ((u >> 16) & 1u)) >> 16;
    return (u16)r;
}
static __device__ __forceinline__ float bf2f(u16 u) {
    return __uint_as_float(((unsigned)u) << 16);
}
static __device__ __forceinline__ float fexp2(float x) {   // native v_exp_f32 = 2^x
    float r; asm("v_exp_f32 %0, %1" : "=v"(r) : "v"(x)); return r;
}

static __device__ __forceinline__ f32x4 mfma16(bf16x8 a, bf16x8 b, f32x4 c) {
    return __builtin_amdgcn_mfma_f32_16x16x32_bf16(a, b, c, 0, 0, 0);
}

// Fragment-swizzled layouts (u16 offsets within one batch):
static __device__ __forceinline__ int swzQK(int row, int col) {
    return ((row >> 4) * 8 + (col >> 5)) * 512 + ((col >> 3) & 3) * 128 + (row & 15) * 8 + (col & 7);
}
static __device__ __forceinline__ int swzV(int d, int j) {
    return ((j >> 5) * 16 + (d >> 4)) * 512 + ((j >> 3) & 3) * 128 + (d & 15) * 8 + (j & 7);
}

typedef const __attribute__((address_space(1))) void* gas1_t;
typedef __attribute__((address_space(3))) void* las3_t;
static __device__ __forceinline__ void gll16(const u16* g, u16* l) {
    __builtin_amdgcn_global_load_lds((gas1_t)(const void*)g, (las3_t)(void*)l, 16, 0, 0);
}

// ---------------- kernel 1: weights f32 -> bf16 (K pre-scaled by log2e) ----------------
__global__ void wconv_kernel(const float* __restrict__ wq, const float* __restrict__ wk,
                             const float* __restrict__ wv,
                             u16* __restrict__ wqb, u16* __restrict__ wkb, u16* __restrict__ wvb) {
    int i = blockIdx.x * blockDim.x + threadIdx.x;
    wqb[i] = f2bf(wq[i]);
    wkb[i] = f2bf(wk[i] * LOG2E);
    wvb[i] = f2bf(wv[i]);
}

// ---------------- kernel 2: pose [B,C,N] f32 -> poseT [B,N,C] bf16 ----------------
__global__ void transpose_kernel(const float* __restrict__ pose, u16* __restrict__ poseT) {
    __shared__ float tile[64][65];
    int bid = blockIdx.x;              // B * 4 * 64 = 1024
    int b = bid >> 8;
    int rem = bid & 255;
    int ct = rem >> 6;
    int nt = rem & 63;
    int c0 = ct * 64, n0 = nt * 64;
    int tid = threadIdx.x;
    int lo = tid & 63, hi = tid >> 6;
#pragma unroll
    for (int r = 0; r < 16; ++r) {
        int cc = r * 4 + hi;
        tile[cc][lo] = pose[(size_t)(b * C_ + c0 + cc) * N_ + n0 + lo];
    }
    __syncthreads();
#pragma unroll
    for (int r = 0; r < 16; ++r) {
        int nn = r * 4 + hi;
        poseT[(size_t)(b * N_ + n0 + nn) * C_ + c0 + lo] = f2bf(tile[lo][nn]);
    }
}

// ---------------- kernel 3: projections (fragment-swizzled outputs) ----------------
__global__ __launch_bounds__(256) void proj_kernel(
    const u16* __restrict__ poseT,
    const u16* __restrict__ wqb, const float* __restrict__ bq,
    const u16* __restrict__ wkb, const float* __restrict__ bk,
    const u16* __restrict__ wvb, const float* __restrict__ bv,
    u16* __restrict__ Qm, u16* __restrict__ Km, u16* __restrict__ Vm)
{
    int bid = blockIdx.x;              // B * N/64 = 256
    int b = bid >> 6;
    int n0 = (bid & 63) * 64;
    int lane = threadIdx.x & 63;
    int wav = threadIdx.x >> 6;
    int l15 = lane & 15, lg = lane >> 4;

    int nrow = n0 + wav * 16;
    const u16* arow = poseT + (size_t)(b * N_ + nrow + l15) * C_;
    bf16x8 afr[8];
#pragma unroll
    for (int kc = 0; kc < 8; ++kc)
        afr[kc] = *(const bf16x8*)(arow + kc * 32 + lg * 8);

    for (int qk = 0; qk < 2; ++qk) {
        const u16* wb = qk ? wkb : wqb;
        const float* bias = qk ? bk : bq;
        u16* outm = qk ? Km : Qm;
        float bscale = qk ? LOG2E : 1.0f;
#pragma unroll
        for (int ct = 0; ct < 16; ++ct) {
            f32x4 acc = {0.f, 0.f, 0.f, 0.f};
            const u16* brow = wb + (size_t)(ct * 16 + l15) * C_;
#pragma unroll
            for (int kc = 0; kc < 8; ++kc) {
                bf16x8 bfr = *(const bf16x8*)(brow + kc * 32 + lg * 8);
                acc = mfma16(afr[kc], bfr, acc);
            }
            float bias_v = bias[ct * 16 + l15] * bscale;
#pragma unroll
            for (int reg = 0; reg < 4; ++reg) {
                int nr = nrow + lg * 4 + reg;
                outm[(size_t)b * N_ * C_ + swzQK(nr, ct * 16 + l15)] = f2bf(acc[reg] + bias_v);
            }
        }
    }

    int d0w = wav * 64;
#pragma unroll
    for (int dt = 0; dt < 4; ++dt) {
        const u16* awrow = wvb + (size_t)(d0w + dt * 16 + l15) * C_;
        bf16x8 av[8];
#pragma unroll
        for (int kc = 0; kc < 8; ++kc)
            av[kc] = *(const bf16x8*)(awrow + kc * 32 + lg * 8);
#pragma unroll
        for (int nt = 0; nt < 4; ++nt) {
            f32x4 acc = {0.f, 0.f, 0.f, 0.f};
            const u16* brow = poseT + (size_t)(b * N_ + n0 + nt * 16 + l15) * C_;
#pragma unroll
            for (int kc = 0; kc < 8; ++kc) {
                bf16x8 bfr = *(const bf16x8*)(brow + kc * 32 + lg * 8);
                acc = mfma16(av[kc], bfr, acc);
            }
#pragma unroll
            for (int reg = 0; reg < 4; ++reg) {
                int dd = d0w + dt * 16 + lg * 4 + reg;
                Vm[(size_t)b * C_ * N_ + swzV(dd, n0 + nt * 16 + l15)] = f2bf(acc[reg] + bv[dd]);
            }
        }
    }
}

// ---------------- kernel 4: flash attention partial ----------------
// 256 threads = 4 waves x 16 i-rows (64-row i-tile), shared K/V staging (KBLK=32,
// K double-buffered, V overlapped), defer-max softmax, l via ones-MFMA.
// Scores are in log2 domain (K pre-scaled by log2e); exp = v_exp_f32.
// NOTE: bare __launch_bounds__(256) — ",min_waves" hints cap VGPR at 64 (r3/4/5).
// NOTE: no arrays of LDS-derived pointers (r8 compile fail) — named scalars only.
__global__ __launch_bounds__(256) void attn_partial_kernel(
    const u16* __restrict__ Qs, const u16* __restrict__ Ks, const u16* __restrict__ Vs,
    u16* __restrict__ pO, float* __restrict__ pM, float* __restrict__ pL,
    int S, int njt)
{
    __shared__ __align__(16) char smem[49152];   // K dbuf 2x16KB | V 16KB ; epilogue obuf aliases
    __shared__ __align__(16) u16 Plds[4][16][40];

    u16* Klds0 = (u16*)smem;
    u16* Klds1 = (u16*)(smem + 16384);
    u16* Vb = (u16*)(smem + 32768);

    int G = B_ * S;
    int bid = blockIdx.x;               // 64 * G
    int g = bid % G;                    // blocks with same g share a K/V slice
    int pos = bid / G;                  // 0..63 i-tile
    int b = g / S;
    int s = g % S;
    int i0 = pos * 64;

    int tid = threadIdx.x;
    int lane = tid & 63;
    int w = tid >> 6;                   // i-subtile 0..3
    int l15 = lane & 15, lg = lane >> 4;

    const u16* Qb = Qs + (size_t)b * N_ * C_ + (size_t)(pos * 4 + w) * 4096 + lane * 8;
    bf16x8 qf[8];
#pragma unroll
    for (int kc = 0; kc < 8; ++kc) qf[kc] = *(const bf16x8*)(Qb + kc * 512);

    bf16x8 b_ones;
#pragma unroll
    for (int e = 0; e < 8; ++e) b_ones[e] = (short)0x3F80;   // bf16 1.0

    f32x4 Ot[16];
#pragma unroll
    for (int ct = 0; ct < 16; ++ct) Ot[ct] = (f32x4){0.f, 0.f, 0.f, 0.f};
    f32x4 Lacc = {0.f, 0.f, 0.f, 0.f};
    float m_r[4] = {-1e30f, -1e30f, -1e30f, -1e30f};

    const u16* Kbase = Ks + (size_t)b * N_ * C_;
    const u16* Vbase = Vs + (size_t)b * C_ * N_;
    int halfN = N_ / S;

    // prologue: stage tile 0
    {
        const u16* Ksrc = Kbase + (size_t)((s * halfN) >> 4) * 4096;
        const u16* Vsrc = Vbase + (size_t)((s * halfN) >> 5) * 8192;
#pragma unroll
        for (int q = 0; q < 4; ++q) {
            int v = q * 256 + tid;
            gll16(Ksrc + v * 8, Klds0 + v * 8);
            gll16(Vsrc + v * 8, Vb + v * 8);
        }
    }

    for (int jt = 0; jt < njt; ++jt) {
        u16* Kcur = (jt & 1) ? Klds1 : Klds0;
        u16* Knxt = (jt & 1) ? Klds0 : Klds1;
        __syncthreads();                           // K(jt), V(jt) landed; all waves synced

        if (jt + 1 < njt) {                        // stage K(jt+1) into idle buffer (hidden under compute)
            const u16* Ksrc = Kbase + (size_t)((s * halfN + (jt + 1) * 32) >> 4) * 4096;
#pragma unroll
            for (int q = 0; q < 4; ++q) {
                int v = q * 256 + tid;
                gll16(Ksrc + v * 8, Knxt + v * 8);
            }
        }

        // QK^T: rows = i (lg*4+reg), cols = j (l15 | +16)
        f32x4 sc0 = {0.f, 0.f, 0.f, 0.f}, sc1 = {0.f, 0.f, 0.f, 0.f};
#pragma unroll
        for (int kc = 0; kc < 8; ++kc) {
            bf16x8 k0 = *(const bf16x8*)(Kcur + kc * 512 + lane * 8);
            bf16x8 k1 = *(const bf16x8*)(Kcur + 4096 + kc * 512 + lane * 8);
            sc0 = mfma16(qf[kc], k0, sc0);
            sc1 = mfma16(qf[kc], k1, sc1);
        }

        // defer-max check (wave-uniform)
        bool ok = true;
#pragma unroll
        for (int reg = 0; reg < 4; ++reg) {
            float lim = m_r[reg] + THR_L2;
            ok = ok && (sc0[reg] <= lim) && (sc1[reg] <= lim);
        }
        if (!__all(ok)) {
            // slow path: full row-max reduce + rescale O and L
#pragma unroll
            for (int reg = 0; reg < 4; ++reg) {
                float rm = fmaxf(sc0[reg], sc1[reg]);
                rm = fmaxf(rm, __shfl_xor(rm, 1));
                rm = fmaxf(rm, __shfl_xor(rm, 2));
                rm = fmaxf(rm, __shfl_xor(rm, 4));
                rm = fmaxf(rm, __shfl_xor(rm, 8));
                float mn = fmaxf(m_r[reg], rm);
                float scale = fexp2(m_r[reg] - mn);
                m_r[reg] = mn;
                Lacc[reg] *= scale;
#pragma unroll
                for (int ct = 0; ct < 16; ++ct) Ot[ct][reg] *= scale;
            }
        }

        // P = 2^(s - m), bf16, -> Plds
#pragma unroll
        for (int reg = 0; reg < 4; ++reg) {
            Plds[w][lg * 4 + reg][l15]      = f2bf(fexp2(sc0[reg] - m_r[reg]));
            Plds[w][lg * 4 + reg][16 + l15] = f2bf(fexp2(sc1[reg] - m_r[reg]));
        }
        bf16x8 af = *(const bf16x8*)(&Plds[w][l15][lg * 8]);

        Lacc = mfma16(af, b_ones, Lacc);           // row-sum of quantized P

        // PV
#pragma unroll
        for (int ct = 0; ct < 16; ++ct) {
            bf16x8 vf = *(const bf16x8*)(Vb + ct * 512 + lane * 8);
            Ot[ct] = mfma16(af, vf, Ot[ct]);
        }
        __syncthreads();                           // Vb consumed by all waves

        if (jt + 1 < njt) {                        // stage V(jt+1); lands by next top barrier
            const u16* Vsrc = Vbase + (size_t)((s * halfN + (jt + 1) * 32) >> 5) * 8192;
#pragma unroll
            for (int q = 0; q < 4; ++q) {
                int v = q * 256 + tid;
                gll16(Vsrc + v * 8, Vb + v * 8);
            }
        }
    }

    // ---- epilogue ----
    size_t rowb = (size_t)(s * B_ + b) * N_ + i0 + w * 16;
    if (l15 == 0) {
#pragma unroll
        for (int reg = 0; reg < 4; ++reg) {
            pM[rowb + lg * 4 + reg] = m_r[reg];
            pL[rowb + lg * 4 + reg] = Lacc[reg];
        }
    }
    float* obuf = (float*)smem;   // [64][66]
    size_t prow = (size_t)(s * B_ + b) * N_ + i0;
#pragma unroll
    for (int cc = 0; cc < 4; ++cc) {
#pragma unroll
        for (int u = 0; u < 4; ++u)
#pragma unroll
            for (int reg = 0; reg < 4; ++reg)
                obuf[(w * 16 + lg * 4 + reg) * 66 + u * 16 + l15] = Ot[cc * 4 + u][reg];
        __syncthreads();
#pragma unroll
        for (int h = 0; h < 2; ++h) {
            int v = h * 256 + tid;
            int row = v >> 3, cg = v & 7;
            const float* src = obuf + row * 66 + cg * 8;
            u32x4 pk;
#pragma unroll
            for (int k = 0; k < 4; ++k)
                pk[k] = (unsigned)f2bf(src[2 * k]) | ((unsigned)f2bf(src[2 * k + 1]) << 16);
            *(u32x4*)(pO + (prow + row) * C_ + cc * 64 + cg * 8) = pk;
        }
        __syncthreads();
    }
}

// ---------------- kernel 5: combine partials + residual (log2-domain m) ----------------
__global__ __launch_bounds__(256) void combine_kernel(
    const u16* __restrict__ pO, const float* __restrict__ pM, const float* __restrict__ pL,
    const float* __restrict__ pose, const float* __restrict__ gamma_p,
    float* __restrict__ out, int S)
{
    __shared__ float a_s[4][64];
    __shared__ float tile[64][65];

    int bid = blockIdx.x;              // B*4*64 = 1024
    int b = bid >> 8;
    int ct = (bid >> 6) & 3;
    int it = bid & 63;
    int c0 = ct * 64, i0 = it * 64;
    int tid = threadIdx.x;

    if (tid < 64) {
        int i = i0 + tid;
        float M = -1e30f;
        for (int s = 0; s < S; ++s)
            M = fmaxf(M, pM[(size_t)(s * B_ + b) * N_ + i]);
        float L = 0.f;
        for (int s = 0; s < S; ++s) {
            size_t idx = (size_t)(s * B_ + b) * N_ + i;
            L += pL[idx] * fexp2(pM[idx] - M);
        }
        float invL = 1.0f / L;
        for (int s = 0; s < S; ++s) {
            size_t idx = (size_t)(s * B_ + b) * N_ + i;
            a_s[s][tid] = fexp2(pM[idx] - M) * invL;
        }
    }
    __syncthreads();

    int lane = tid & 63, hi = tid >> 6;
#pragma unroll
    for (int r = 0; r < 16; ++r) {
        int il = r * 4 + hi;
        float acc = 0.f;
        for (int s = 0; s < S; ++s) {
            u16 u = pO[((size_t)(s * B_ + b) * N_ + i0 + il) * C_ + c0 + lane];
            acc += a_s[s][il] * bf2f(u);
        }
        tile[il][lane] = acc;
    }
    __syncthreads();

    float g = gamma_p[0];
#pragma unroll
    for (int r = 0; r < 16; ++r) {
        int cc = r * 4 + hi;
        size_t addr = (size_t)(b * C_ + c0 + cc) * N_ + i0 + lane;
        out[addr] = pose[addr] + g * tile[lane][cc];
    }
}

extern "C" void kernel_launch(void* const* d_in, const int* in_sizes, int n_in,
                              void* d_out, int out_size, void* d_ws, size_t ws_size,
                              hipStream_t stream) {
    (void)in_sizes; (void)n_in; (void)out_size;
    const float* pose = (const float*)d_in[0];
    const float* wq = (const float*)d_in[1];
    const float* bq = (const float*)d_in[2];
    const float* wk = (const float*)d_in[3];
    const float* bk = (const float*)d_in[4];
    const float* wv = (const float*)d_in[5];
    const float* bv = (const float*)d_in[6];
    const float* gamma = (const float*)d_in[7];
    float* out = (float*)d_out;

    const int S = 2;   // global j-split (ws-limited; LDS caps blocks/CU at 2 anyway)
    char* ws = (char*)d_ws;
    u16* wqb   = (u16*)(ws + 0);
    u16* wkb   = (u16*)(ws + (128 << 10));
    u16* wvb   = (u16*)(ws + (256 << 10));
    float* pM  = (float*)(ws + (384 << 10));
    float* pL  = pM + (size_t)S * B_ * N_;
    u16* Qm    = (u16*)(ws + (1 << 20));     // 8 MB (swizzled)
    u16* Km    = (u16*)(ws + (9 << 20));     // 8 MB (swizzled, log2e-scaled)
    u16* Vm    = (u16*)(ws + (17 << 20));    // 8 MB (swizzled)
    u16* poseT = (u16*)(ws + (25 << 20));    // 8 MB (dead after proj)
    u16* pO    = (u16*)(ws + (25 << 20));    // S*8 MB, aliases poseT

    int njt = (N_ / S) / 32;

    hipLaunchKernelGGL(wconv_kernel, dim3(256), dim3(256), 0, stream, wq, wk, wv, wqb, wkb, wvb);
    hipLaunchKernelGGL(transpose_kernel, dim3(1024), dim3(256), 0, stream, pose, poseT);
    hipLaunchKernelGGL(proj_kernel, dim3(256), dim3(256), 0, stream,
                       poseT, wqb, bq, wkb, bk, wvb, bv, Qm, Km, Vm);
    hipLaunchKernelGGL(attn_partial_kernel, dim3(64 * B_ * S), dim3(256), 0, stream,
                       Qm, Km, Vm, pO, pM, pL, S, njt);
    hipLaunchKernelGGL(combine_kernel, dim3(1024), dim3(256), 0, stream,
                       pO, pM, pL, pose, gamma, out, S);
}